// Round 3
// baseline (1010.897 us; speedup 1.0000x reference)
//
#include <hip/hip_runtime.h>
#include <hip/hip_bf16.h>
#include <stdint.h>

#define D_DIM 1024
#define H_HEADS 16
#define HD 64
#define E_EXP 8
#define B_BATCH 2
#define N_SEQ 2048
#define M_KV 4096
#define CHUNK 512
#define TOK (B_BATCH*N_SEQ)
#define KROWS (B_BATCH*CHUNK)
#define LISTROWS 10240  // >= TOK*2 + 16*127 padded rows

typedef unsigned short u16;
typedef __attribute__((ext_vector_type(8))) short bf16x8;
typedef __attribute__((ext_vector_type(4))) float f32x4;
typedef __attribute__((ext_vector_type(4))) short shortx4;

__device__ __forceinline__ u16 f2bfu(float x) {
  unsigned int u = __float_as_uint(x);
  u += 0x7FFF + ((u >> 16) & 1);
  return (u16)(u >> 16);
}

__device__ __forceinline__ void gload_lds16(const u16* g, char* lds_base) {
  __builtin_amdgcn_global_load_lds(
      (const __attribute__((address_space(1))) void*)g,
      (__attribute__((address_space(3))) void*)lds_base, 16, 0, 0);
}

// ---------------- utility kernels ----------------

__global__ void zero_f32(float4* out, int n4) {
  int i = blockIdx.x * 256 + threadIdx.x;
  if (i < n4) out[i] = make_float4(0.f, 0.f, 0.f, 0.f);
}

__global__ void zero_aux(int* p) { p[threadIdx.x] = 0; }  // 64 threads

__global__ void cast_bf16(const float4* __restrict__ in, shortx4* __restrict__ out, int n4) {
  int i = blockIdx.x * 256 + threadIdx.x;
  if (i < n4) {
    float4 v = in[i];
    shortx4 p;
    p[0] = (short)f2bfu(v.x); p[1] = (short)f2bfu(v.y);
    p[2] = (short)f2bfu(v.z); p[3] = (short)f2bfu(v.w);
    out[i] = p;
  }
}

// W[e][k][n] fp32 -> Wt[e][n][k] bf16
__global__ void transpose_cast_w(const float* __restrict__ W, u16* __restrict__ Wt) {
  __shared__ float tile[32][33];
  const int e = blockIdx.z;
  const int kb = blockIdx.x * 32;
  const int nb = blockIdx.y * 32;
  const int tx = threadIdx.x & 31, ty = threadIdx.x >> 5;
  const float* Wp = W + (long)e * D_DIM * D_DIM;
  u16* Wtp = Wt + (long)e * D_DIM * D_DIM;
#pragma unroll
  for (int i = 0; i < 4; i++) {
    int r = ty + i * 8;
    tile[r][tx] = Wp[(long)(kb + r) * D_DIM + nb + tx];
  }
  __syncthreads();
#pragma unroll
  for (int i = 0; i < 4; i++) {
    int n = ty + i * 8;
    Wtp[(long)(nb + n) * D_DIM + kb + tx] = f2bfu(tile[tx][n]);
  }
}

// ---------------- router (wgate dense + top2 idx + per-(e,b) counts) ----------------
__launch_bounds__(256)
__global__ void router_kernel(const float* __restrict__ q, const float* __restrict__ Wr,
                              const float* __restrict__ br, float* __restrict__ wgate,
                              int* __restrict__ eIdx, int* __restrict__ segMeta) {
  const int lane = threadIdx.x & 63, w = threadIdx.x >> 6;
  const int token = blockIdx.x * 4 + w;
  float acc[E_EXP];
#pragma unroll
  for (int e = 0; e < 8; e++) acc[e] = 0.f;
  const float* qp = q + (long)token * D_DIM;
  for (int it = 0; it < 16; it++) {
    int d = it * 64 + lane;
    float qv = qp[d];
    const float4* wr4 = (const float4*)(Wr + (long)d * 8);
    float4 w0 = wr4[0], w1 = wr4[1];
    acc[0] += qv * w0.x; acc[1] += qv * w0.y; acc[2] += qv * w0.z; acc[3] += qv * w0.w;
    acc[4] += qv * w1.x; acc[5] += qv * w1.y; acc[6] += qv * w1.z; acc[7] += qv * w1.w;
  }
#pragma unroll
  for (int e = 0; e < 8; e++)
    for (int off = 32; off; off >>= 1) acc[e] += __shfl_down(acc[e], off);
  if (lane == 0) {
    float lg[8];
#pragma unroll
    for (int e = 0; e < 8; e++) lg[e] = acc[e] + br[e];
    int i0 = 0;
#pragma unroll
    for (int e = 1; e < 8; e++) if (lg[e] > lg[i0]) i0 = e;
    int i1 = (i0 == 0) ? 1 : 0;
#pragma unroll
    for (int e = 0; e < 8; e++) if (e != i0 && lg[e] > lg[i1]) i1 = e;
    float w0v = 1.f / (1.f + __expf(lg[i1] - lg[i0]));
    float wv[8];
#pragma unroll
    for (int e = 0; e < 8; e++) wv[e] = 0.f;
    wv[i0] = w0v; wv[i1] = 1.f - w0v;
#pragma unroll
    for (int e = 0; e < 8; e++) wgate[(long)token * 8 + e] = wv[e];
    eIdx[token * 2] = i0; eIdx[token * 2 + 1] = i1;
    int b = token >> 11;
    atomicAdd(&segMeta[32 + i0 * 2 + b], 1);
    atomicAdd(&segMeta[32 + i1 * 2 + b], 1);
  }
}

// segMeta layout: [0:16) segStart, [16:32) segPad, [32:48) cnt, [48:64) fill
__global__ void prefix_kernel(int* segMeta) {
  if (threadIdx.x == 0) {
    int s = 0;
    for (int i = 0; i < 16; i++) {
      int c = segMeta[32 + i];
      int p = (c + 127) & ~127;
      segMeta[i] = s; segMeta[16 + i] = p; s += p;
    }
  }
}

__global__ void scatter_kernel(const int* __restrict__ eIdx, int* __restrict__ segMeta,
                               int* __restrict__ tokList) {
  int t0 = blockIdx.x * 256 + threadIdx.x;
  if (t0 >= TOK) return;
  int b = t0 >> 11;
  for (int k = 0; k < 2; k++) {
    int e = eIdx[t0 * 2 + k];
    int eb = e * 2 + b;
    int pos = atomicAdd(&segMeta[48 + eb], 1);
    tokList[segMeta[eb] + pos] = t0;
  }
}

// ---------------- GEMM: C[M,N] = A[M,K=1024] x Bt[N,K=1024]^T (+bias) ----------------
// AMAP: 0 linear A rows (z=expert); 1 expert-chunk gather (z=expert);
//       2 tokList gather (z=eb segment); 3 segment-linear rows (z=eb segment)
// EPI : 0 bf16 C (+bias); 1 bf16 C transposed per batch; 2 dense gated fp32 atomic;
//       3 sparse gated fp32 atomic via tokList
template<int AMAP, int EPI>
__launch_bounds__(256)
__global__ void gemm_bt(const u16* __restrict__ A, long aLeStride,
                        const u16* __restrict__ Bt, const float* __restrict__ bias,
                        u16* __restrict__ Cb, long cLeStride,
                        const float* __restrict__ wgate, float* __restrict__ outAcc,
                        int e0, const int* __restrict__ segMeta,
                        const int* __restrict__ tokList) {
  __shared__ u16 As[128 * 32];
  __shared__ u16 Bs[128 * 32];
  const int t = threadIdx.x;
  const int lane = t & 63, w = t >> 6;
  const int le = blockIdx.z;
  int e; long rowBase = 0; int segCnt = 0;
  if (AMAP >= 2) {
    e = le >> 1;
    int sp = segMeta[16 + le];
    if ((int)(blockIdx.x * 128) >= sp) return;
    rowBase = segMeta[le]; segCnt = segMeta[32 + le];
  } else {
    e = e0 + le;
  }
  const long row0 = (long)blockIdx.x * 128;
  const long col0 = (long)blockIdx.y * 128;

  const u16* Ap = (AMAP <= 1) ? (A + (long)le * aLeStride) : A;
  const u16* Btp = Bt + (long)e * D_DIM * D_DIM;
  const float* biasp = bias + (long)e * D_DIM;

  const u16* aSrc[2];
  const u16* bSrc[2];
#pragma unroll
  for (int i = 0; i < 2; i++) {
    int o = i * 4096 + t * 16;
    int r = o >> 6;
    int slot = ((o >> 4) & 3) ^ ((r >> 1) & 3);
    long r_loc = row0 + r;
    long arow;
    if (AMAP == 1) arow = (r_loc >> 9) * M_KV + (long)e * CHUNK + (r_loc & 511);
    else if (AMAP == 2) arow = tokList[rowBase + (r_loc < segCnt ? r_loc : (long)(segCnt - 1))];
    else if (AMAP == 3) arow = rowBase + r_loc;
    else arow = r_loc;
    aSrc[i] = Ap + arow * D_DIM + slot * 8;
    bSrc[i] = Btp + (col0 + r) * D_DIM + slot * 8;
  }

  f32x4 acc[4][4];
#pragma unroll
  for (int i = 0; i < 4; i++)
#pragma unroll
    for (int j = 0; j < 4; j++) acc[i][j] = (f32x4){0.f, 0.f, 0.f, 0.f};

  const int wr = (w >> 1) * 64, wc = (w & 1) * 64;
  const int fr = lane & 15, fs = lane >> 4;
  int aoff[4], boff[4];
#pragma unroll
  for (int mi = 0; mi < 4; mi++) { int r = wr + mi * 16 + fr; aoff[mi] = r * 32 + ((fs ^ ((r >> 1) & 3)) * 8); }
#pragma unroll
  for (int ni = 0; ni < 4; ni++) { int r = wc + ni * 16 + fr; boff[ni] = r * 32 + ((fs ^ ((r >> 1) & 3)) * 8); }

  char* ldsA = (char*)As + w * 1024;
  char* ldsB = (char*)Bs + w * 1024;

  for (int kb = 0; kb < 32; kb++) {
    __syncthreads();
#pragma unroll
    for (int i = 0; i < 2; i++) gload_lds16(aSrc[i] + kb * 32, ldsA + i * 4096);
#pragma unroll
    for (int i = 0; i < 2; i++) gload_lds16(bSrc[i] + kb * 32, ldsB + i * 4096);
    __syncthreads();
    bf16x8 af[4], bff[4];
#pragma unroll
    for (int mi = 0; mi < 4; mi++) af[mi] = *(const bf16x8*)(As + aoff[mi]);
#pragma unroll
    for (int ni = 0; ni < 4; ni++) bff[ni] = *(const bf16x8*)(Bs + boff[ni]);
#pragma unroll
    for (int mi = 0; mi < 4; mi++)
#pragma unroll
      for (int ni = 0; ni < 4; ni++)
        acc[mi][ni] = __builtin_amdgcn_mfma_f32_16x16x32_bf16(af[mi], bff[ni], acc[mi][ni], 0, 0, 0);
  }

#pragma unroll
  for (int ni = 0; ni < 4; ni++) {
    long c = col0 + wc + ni * 16 + fr;
    float bv = biasp[c];
#pragma unroll
    for (int mi = 0; mi < 4; mi++) {
      long r0g = row0 + wr + mi * 16 + fs * 4;
      f32x4 v = acc[mi][ni];
      if (EPI == 0) {
        u16* Cp = Cb + (AMAP >= 2 ? rowBase * D_DIM : (long)le * cLeStride);
#pragma unroll
        for (int j = 0; j < 4; j++) Cp[(r0g + j) * D_DIM + c] = f2bfu(v[j] + bv);
      } else if (EPI == 1) {
        u16* Cp = Cb + (long)le * cLeStride;
        long b = r0g >> 9, m0 = r0g & 511;
        shortx4 pk;
#pragma unroll
        for (int j = 0; j < 4; j++) pk[j] = (short)f2bfu(v[j] + bv);
        *(shortx4*)(Cp + (b * D_DIM + c) * CHUNK + m0) = pk;
      } else if (EPI == 2) {
#pragma unroll
        for (int j = 0; j < 4; j++) {
          long r = r0g + j;
          float wv = wgate[r * E_EXP + e];
          if (wv != 0.f) atomicAdd(outAcc + r * D_DIM + c, wv * (v[j] + bv));
        }
      } else {
#pragma unroll
        for (int j = 0; j < 4; j++) {
          long rl = r0g + j;
          if (rl < segCnt) {
            int tok = tokList[rowBase + rl];
            float wv = wgate[(long)tok * E_EXP + e];
            atomicAdd(outAcc + (long)tok * D_DIM + c, wv * (v[j] + bv));
          }
        }
      }
    }
  }
}

// ---------------- fused attention ----------------
// GATHER=0: z=expert-slot, y=b*16+h, Q rows dense. GATHER=1: z=eb segment, y=h, Q rows gathered.
template<int GATHER>
__launch_bounds__(256)
__global__ void attn_kernel(const u16* __restrict__ Qp, const u16* __restrict__ Kp,
                            const u16* __restrict__ Vt, u16* __restrict__ AO,
                            const int* __restrict__ segMeta) {
  __shared__ u16 Qs[64 * 64];
  __shared__ u16 Ks[128 * 64];
  __shared__ u16 Vs[64 * 128];
  __shared__ u16 Ps[4][16 * 128];

  const int t = threadIdx.x, lane = t & 63, w = t >> 6;

  const u16 *Qbase, *Kbase, *Vbase;
  u16* AObase;
  if (GATHER) {
    const int eb = blockIdx.z, e = eb >> 1, b = eb & 1, h = blockIdx.y;
    int sp = segMeta[16 + eb];
    if ((int)(blockIdx.x * 64) >= sp) return;
    long qrow0 = segMeta[eb] + blockIdx.x * 64;
    Qbase = Qp + qrow0 * D_DIM + h * HD;
    Kbase = Kp + ((long)e * KROWS + (long)b * CHUNK) * D_DIM + h * HD;
    Vbase = Vt + ((long)e * B_BATCH + b) * (long)D_DIM * CHUNK + (long)h * HD * CHUNK;
    AObase = AO + qrow0 * D_DIM + h * HD;
  } else {
    const int qb0 = blockIdx.x * 64;
    const int b = blockIdx.y >> 4, h = blockIdx.y & 15;
    const int le = blockIdx.z;
    Qbase = Qp + (long)le * TOK * D_DIM + ((long)b * N_SEQ + qb0) * D_DIM + h * HD;
    Kbase = Kp + (long)le * KROWS * D_DIM + (long)b * CHUNK * D_DIM + h * HD;
    Vbase = Vt + ((long)le * B_BATCH + b) * (long)D_DIM * CHUNK + (long)h * HD * CHUNK;
    AObase = AO + (long)le * TOK * D_DIM + ((long)b * N_SEQ + qb0) * D_DIM + h * HD;
  }

#pragma unroll
  for (int i = 0; i < 2; i++) {
    int o = i * 4096 + t * 16;
    int r = o >> 7;
    int slot = ((o >> 4) & 7) ^ (r & 7);
    gload_lds16(Qbase + (long)r * D_DIM + slot * 8, (char*)Qs + w * 1024 + i * 4096);
  }

  const int fr = lane & 15, fs = lane >> 4;
  const int qrow = w * 16 + fr;
  int qoff[2];
#pragma unroll
  for (int ks = 0; ks < 2; ks++) qoff[ks] = qrow * 64 + (((ks * 4 + fs) ^ (qrow & 7)) * 8);
  int koff[8][2];
#pragma unroll
  for (int g = 0; g < 8; g++)
#pragma unroll
    for (int ks = 0; ks < 2; ks++) {
      int r = g * 16 + fr;
      koff[g][ks] = r * 64 + (((ks * 4 + fs) ^ (r & 7)) * 8);
    }
  int voff[4][4];
#pragma unroll
  for (int ni = 0; ni < 4; ni++)
#pragma unroll
    for (int ks = 0; ks < 4; ks++) {
      int r = ni * 16 + fr;
      voff[ni][ks] = r * 128 + (((ks * 4 + fs) ^ (r & 7)) * 8);
    }
  int poff[4];
#pragma unroll
  for (int ks = 0; ks < 4; ks++) poff[ks] = fr * 128 + (((ks * 4 + fs) ^ (fr & 7)) * 8);

  float mrun[4], lsum[4];
#pragma unroll
  for (int j = 0; j < 4; j++) { mrun[j] = -1e30f; lsum[j] = 0.f; }
  f32x4 oacc[4];
#pragma unroll
  for (int ni = 0; ni < 4; ni++) oacc[ni] = (f32x4){0.f, 0.f, 0.f, 0.f};

  for (int mt = 0; mt < 4; mt++) {
    __syncthreads();
#pragma unroll
    for (int i = 0; i < 4; i++) {
      int o = i * 4096 + t * 16;
      int r = o >> 7;
      int slot = ((o >> 4) & 7) ^ (r & 7);
      gload_lds16(Kbase + (long)(mt * 128 + r) * D_DIM + slot * 8, (char*)Ks + w * 1024 + i * 4096);
    }
#pragma unroll
    for (int i = 0; i < 4; i++) {
      int o = i * 4096 + t * 16;
      int r = o >> 8;
      int slot = ((o >> 4) & 15) ^ (r & 7);
      gload_lds16(Vbase + (long)r * CHUNK + mt * 128 + slot * 8, (char*)Vs + w * 1024 + i * 4096);
    }
    __syncthreads();

    f32x4 s[8];
#pragma unroll
    for (int g = 0; g < 8; g++) s[g] = (f32x4){0.f, 0.f, 0.f, 0.f};
#pragma unroll
    for (int ks = 0; ks < 2; ks++) {
      bf16x8 aq = *(const bf16x8*)(Qs + qoff[ks]);
#pragma unroll
      for (int g = 0; g < 8; g++) {
        bf16x8 bk = *(const bf16x8*)(Ks + koff[g][ks]);
        s[g] = __builtin_amdgcn_mfma_f32_16x16x32_bf16(aq, bk, s[g], 0, 0, 0);
      }
    }
#pragma unroll
    for (int g = 0; g < 8; g++) s[g] *= 0.125f;

    float tmax[4];
#pragma unroll
    for (int j = 0; j < 4; j++) {
      float mx = s[0][j];
#pragma unroll
      for (int g = 1; g < 8; g++) mx = fmaxf(mx, s[g][j]);
      tmax[j] = mx;
    }
    for (int off = 1; off < 16; off <<= 1)
#pragma unroll
      for (int j = 0; j < 4; j++) tmax[j] = fmaxf(tmax[j], __shfl_xor(tmax[j], off));

    float corr[4];
#pragma unroll
    for (int j = 0; j < 4; j++) {
      float mn = fmaxf(mrun[j], tmax[j]);
      corr[j] = __expf(mrun[j] - mn);
      mrun[j] = mn;
    }
#pragma unroll
    for (int ni = 0; ni < 4; ni++)
#pragma unroll
      for (int j = 0; j < 4; j++) oacc[ni][j] *= corr[j];

    float psum[4] = {0.f, 0.f, 0.f, 0.f};
#pragma unroll
    for (int g = 0; g < 8; g++) {
#pragma unroll
      for (int j = 0; j < 4; j++) {
        float p = __expf(s[g][j] - mrun[j]);
        psum[j] += p;
        int prow = fs * 4 + j;
        int slot = (g * 2 + (fr >> 3)) ^ (prow & 7);
        Ps[w][prow * 128 + slot * 8 + (fr & 7)] = f2bfu(p);
      }
    }
#pragma unroll
    for (int j = 0; j < 4; j++) lsum[j] = lsum[j] * corr[j] + psum[j];

#pragma unroll
    for (int ks = 0; ks < 4; ks++) {
      bf16x8 ap = *(const bf16x8*)(&Ps[w][poff[ks]]);
#pragma unroll
      for (int ni = 0; ni < 4; ni++) {
        bf16x8 bvv = *(const bf16x8*)(Vs + voff[ni][ks]);
        oacc[ni] = __builtin_amdgcn_mfma_f32_16x16x32_bf16(ap, bvv, oacc[ni], 0, 0, 0);
      }
    }
  }

  for (int off = 1; off < 16; off <<= 1)
#pragma unroll
    for (int j = 0; j < 4; j++) lsum[j] += __shfl_xor(lsum[j], off);

#pragma unroll
  for (int ni = 0; ni < 4; ni++) {
    int c = ni * 16 + fr;
#pragma unroll
    for (int j = 0; j < 4; j++) {
      int qr = w * 16 + fs * 4 + j;
      AObase[(long)qr * D_DIM + c] = f2bfu(oacc[ni][j] / lsum[j]);
    }
  }
}

// ---------------- launcher ----------------
extern "C" void kernel_launch(void* const* d_in, const int* in_sizes, int n_in,
                              void* d_out, int out_size, void* d_ws, size_t ws_size,
                              hipStream_t stream) {
  const float* qf = (const float*)d_in[0];
  const float* kf = (const float*)d_in[1];
  const float* vf = (const float*)d_in[2];
  const float* Wq = (const float*)d_in[3];
  const float* bq = (const float*)d_in[4];
  const float* Wk = (const float*)d_in[5];
  const float* bk = (const float*)d_in[6];
  const float* Wv = (const float*)d_in[7];
  const float* bv = (const float*)d_in[8];
  const float* Wo = (const float*)d_in[9];
  const float* bo = (const float*)d_in[10];
  const float* Wr = (const float*)d_in[11];
  const float* br = (const float*)d_in[12];
  float* out = (float*)d_out;

  char* base = (char*)d_ws;
  size_t off = 0;
  auto alloc = [&](size_t bytes) {
    void* r = base + off;
    off += (bytes + 255) & ~(size_t)255;
    return r;
  };
  // common buffers
  u16* qb = (u16*)alloc((size_t)TOK * D_DIM * 2);
  u16* kb = (u16*)alloc((size_t)B_BATCH * M_KV * D_DIM * 2);
  u16* vb = (u16*)alloc((size_t)B_BATCH * M_KV * D_DIM * 2);
  u16* Wqt = (u16*)alloc((size_t)E_EXP * D_DIM * D_DIM * 2);
  u16* Wkt = (u16*)alloc((size_t)E_EXP * D_DIM * D_DIM * 2);
  u16* Wvt = (u16*)alloc((size_t)E_EXP * D_DIM * D_DIM * 2);
  u16* Wot = (u16*)alloc((size_t)E_EXP * D_DIM * D_DIM * 2);
  float* wgate = (float*)alloc((size_t)TOK * E_EXP * 4);
  int* eIdx = (int*)alloc((size_t)TOK * 2 * 4);
  int* segMeta = (int*)alloc(64 * 4);
  int* tokList = (int*)alloc((size_t)LISTROWS * 4);
  const size_t mark = off;

  // sparse-path big buffers (dry-run sizing)
  u16* Qg = (u16*)alloc((size_t)LISTROWS * D_DIM * 2);
  u16* Kp = (u16*)alloc((size_t)E_EXP * KROWS * D_DIM * 2);
  u16* Vtb = (u16*)alloc((size_t)E_EXP * B_BATCH * D_DIM * CHUNK * 2);
  u16* AOg = (u16*)alloc((size_t)LISTROWS * D_DIM * 2);
  const bool sparse = (off <= ws_size);

  // common prologue
  zero_f32<<<TOK * D_DIM / 4 / 256, 256, 0, stream>>>((float4*)out, TOK * D_DIM / 4);
  cast_bf16<<<TOK * D_DIM / 4 / 256, 256, 0, stream>>>((const float4*)qf, (shortx4*)qb, TOK * D_DIM / 4);
  cast_bf16<<<B_BATCH * M_KV * D_DIM / 4 / 256, 256, 0, stream>>>((const float4*)kf, (shortx4*)kb, B_BATCH * M_KV * D_DIM / 4);
  cast_bf16<<<B_BATCH * M_KV * D_DIM / 4 / 256, 256, 0, stream>>>((const float4*)vf, (shortx4*)vb, B_BATCH * M_KV * D_DIM / 4);
  dim3 tg(D_DIM / 32, D_DIM / 32, E_EXP);
  transpose_cast_w<<<tg, 256, 0, stream>>>(Wq, Wqt);
  transpose_cast_w<<<tg, 256, 0, stream>>>(Wk, Wkt);
  transpose_cast_w<<<tg, 256, 0, stream>>>(Wv, Wvt);
  transpose_cast_w<<<tg, 256, 0, stream>>>(Wo, Wot);
  zero_aux<<<1, 64, 0, stream>>>(segMeta);
  router_kernel<<<TOK / 4, 256, 0, stream>>>(qf, Wr, br, wgate, eIdx, segMeta);

  if (sparse) {
    prefix_kernel<<<1, 64, 0, stream>>>(segMeta);
    scatter_kernel<<<TOK / 256, 256, 0, stream>>>(eIdx, segMeta, tokList);
    // dense K/V projections (all experts, each on its own chunk)
    gemm_bt<1, 0><<<dim3(KROWS / 128, 8, E_EXP), 256, 0, stream>>>(
        kb, 0L, Wkt, bk, Kp, (long)KROWS * D_DIM, nullptr, nullptr, 0, nullptr, nullptr);
    gemm_bt<1, 1><<<dim3(KROWS / 128, 8, E_EXP), 256, 0, stream>>>(
        vb, 0L, Wvt, bv, Vtb, (long)B_BATCH * D_DIM * CHUNK, nullptr, nullptr, 0, nullptr, nullptr);
    // gathered Q projection into segment rows
    gemm_bt<2, 0><<<dim3(N_SEQ / 128, 8, 16), 256, 0, stream>>>(
        qb, 0L, Wqt, bq, Qg, 0L, nullptr, nullptr, 0, segMeta, tokList);
    // gathered attention
    attn_kernel<1><<<dim3(N_SEQ / 64, H_HEADS, 16), 256, 0, stream>>>(Qg, Kp, Vtb, AOg, segMeta);
    // gathered gated O projection -> accumulate into out
    gemm_bt<3, 3><<<dim3(N_SEQ / 128, 8, 16), 256, 0, stream>>>(
        AOg, 0L, Wot, bo, nullptr, 0L, wgate, out, 0, segMeta, tokList);
  } else {
    // dense fallback with expert grouping (round-2 verified path)
    off = mark;
    size_t perE = 2 * (size_t)TOK * D_DIM * 2 + (size_t)KROWS * D_DIM * 2 +
                  (size_t)B_BATCH * D_DIM * CHUNK * 2;
    int G = 8;
    while (G > 1 && off + (size_t)G * (perE + 2048) > ws_size) G >>= 1;
    u16* Qp = (u16*)alloc((size_t)G * TOK * D_DIM * 2);
    u16* Kpd = (u16*)alloc((size_t)G * KROWS * D_DIM * 2);
    u16* Vtd = (u16*)alloc((size_t)G * B_BATCH * D_DIM * CHUNK * 2);
    u16* AOb = (u16*)alloc((size_t)G * TOK * D_DIM * 2);
    for (int e0 = 0; e0 < E_EXP; e0 += G) {
      gemm_bt<0, 0><<<dim3(TOK / 128, 8, G), 256, 0, stream>>>(
          qb, 0L, Wqt, bq, Qp, (long)TOK * D_DIM, nullptr, nullptr, e0, nullptr, nullptr);
      gemm_bt<1, 0><<<dim3(KROWS / 128, 8, G), 256, 0, stream>>>(
          kb, 0L, Wkt, bk, Kpd, (long)KROWS * D_DIM, nullptr, nullptr, e0, nullptr, nullptr);
      gemm_bt<1, 1><<<dim3(KROWS / 128, 8, G), 256, 0, stream>>>(
          vb, 0L, Wvt, bv, Vtd, (long)B_BATCH * D_DIM * CHUNK, nullptr, nullptr, e0, nullptr, nullptr);
      attn_kernel<0><<<dim3(N_SEQ / 64, B_BATCH * H_HEADS, G), 256, 0, stream>>>(Qp, Kpd, Vtd, AOb, nullptr);
      gemm_bt<0, 2><<<dim3(TOK / 128, 8, G), 256, 0, stream>>>(
          AOb, (long)TOK * D_DIM, Wot, bo, nullptr, 0L, wgate, out, e0, nullptr, nullptr);
    }
  }
  (void)in_sizes; (void)n_in; (void)out_size;
}

// Round 5
// 893.088 us; speedup vs baseline: 1.1319x; 1.1319x over previous
//
#include <hip/hip_runtime.h>
#include <hip/hip_bf16.h>
#include <stdint.h>

#define D_DIM 1024
#define H_HEADS 16
#define HD 64
#define E_EXP 8
#define B_BATCH 2
#define N_SEQ 2048
#define M_KV 4096
#define CHUNK 512
#define TOK (B_BATCH*N_SEQ)
#define KROWS (B_BATCH*CHUNK)
#define LISTROWS 10240  // >= TOK*2 + 16*127 padded rows

typedef unsigned short u16;
typedef __attribute__((ext_vector_type(8))) short bf16x8;
typedef __attribute__((ext_vector_type(4))) float f32x4;
typedef __attribute__((ext_vector_type(4))) short shortx4;

__device__ __forceinline__ u16 f2bfu(float x) {
  unsigned int u = __float_as_uint(x);
  u += 0x7FFF + ((u >> 16) & 1);
  return (u16)(u >> 16);
}
__device__ __forceinline__ float bf2f(u16 v) {
  return __uint_as_float(((unsigned)v) << 16);
}

__device__ __forceinline__ void gload_lds16(const u16* g, char* lds_base) {
  __builtin_amdgcn_global_load_lds(
      (const __attribute__((address_space(1))) void*)g,
      (__attribute__((address_space(3))) void*)lds_base, 16, 0, 0);
}

// ---------------- utility kernels ----------------

__global__ void zero_f32(float4* out, int n4) {
  int i = blockIdx.x * 256 + threadIdx.x;
  if (i < n4) out[i] = make_float4(0.f, 0.f, 0.f, 0.f);
}

__global__ void zero_aux(int* p) { p[threadIdx.x] = 0; }  // 64 threads

// merged cast of q (4096 f4-blocks), k (8192), v (8192)
__global__ void cast_all(const float4* __restrict__ qf, const float4* __restrict__ kf,
                         const float4* __restrict__ vf, shortx4* __restrict__ qb,
                         shortx4* __restrict__ kb, shortx4* __restrict__ vb) {
  int blk = blockIdx.x;
  const float4* in; shortx4* out; int i;
  if (blk < 4096) { in = qf; out = qb; i = blk * 256 + threadIdx.x; }
  else if (blk < 12288) { in = kf; out = kb; i = (blk - 4096) * 256 + threadIdx.x; }
  else { in = vf; out = vb; i = (blk - 12288) * 256 + threadIdx.x; }
  float4 v = in[i];
  shortx4 p;
  p[0] = (short)f2bfu(v.x); p[1] = (short)f2bfu(v.y);
  p[2] = (short)f2bfu(v.z); p[3] = (short)f2bfu(v.w);
  out[i] = p;
}

// W[e][k][n] fp32 -> Wt[e][n][k] bf16 ; z = which*8 + e
__global__ void transpose_cast_all(const float* __restrict__ Wq, const float* __restrict__ Wk,
                                   const float* __restrict__ Wv, const float* __restrict__ Wo,
                                   u16* __restrict__ Wqt, u16* __restrict__ Wkt,
                                   u16* __restrict__ Wvt, u16* __restrict__ Wot) {
  __shared__ float tile[32][33];
  const int which = blockIdx.z >> 3, e = blockIdx.z & 7;
  const float* W = which == 0 ? Wq : which == 1 ? Wk : which == 2 ? Wv : Wo;
  u16* Wt = which == 0 ? Wqt : which == 1 ? Wkt : which == 2 ? Wvt : Wot;
  const int kb = blockIdx.x * 32;
  const int nb = blockIdx.y * 32;
  const int tx = threadIdx.x & 31, ty = threadIdx.x >> 5;
  const float* Wp = W + (long)e * D_DIM * D_DIM;
  u16* Wtp = Wt + (long)e * D_DIM * D_DIM;
#pragma unroll
  for (int i = 0; i < 4; i++) {
    int r = ty + i * 8;
    tile[r][tx] = Wp[(long)(kb + r) * D_DIM + nb + tx];
  }
  __syncthreads();
#pragma unroll
  for (int i = 0; i < 4; i++) {
    int n = ty + i * 8;
    Wtp[(long)(nb + n) * D_DIM + kb + tx] = f2bfu(tile[tx][n]);
  }
}

// ---------------- router ----------------
__launch_bounds__(256)
__global__ void router_kernel(const float* __restrict__ q, const float* __restrict__ Wr,
                              const float* __restrict__ br, float* __restrict__ wgate,
                              int* __restrict__ eIdx, int* __restrict__ segMeta) {
  const int lane = threadIdx.x & 63, w = threadIdx.x >> 6;
  const int token = blockIdx.x * 4 + w;
  float acc[E_EXP];
#pragma unroll
  for (int e = 0; e < 8; e++) acc[e] = 0.f;
  const float* qp = q + (long)token * D_DIM;
  for (int it = 0; it < 16; it++) {
    int d = it * 64 + lane;
    float qv = qp[d];
    const float4* wr4 = (const float4*)(Wr + (long)d * 8);
    float4 w0 = wr4[0], w1 = wr4[1];
    acc[0] += qv * w0.x; acc[1] += qv * w0.y; acc[2] += qv * w0.z; acc[3] += qv * w0.w;
    acc[4] += qv * w1.x; acc[5] += qv * w1.y; acc[6] += qv * w1.z; acc[7] += qv * w1.w;
  }
#pragma unroll
  for (int e = 0; e < 8; e++)
    for (int off = 32; off; off >>= 1) acc[e] += __shfl_down(acc[e], off);
  if (lane == 0) {
    float lg[8];
#pragma unroll
    for (int e = 0; e < 8; e++) lg[e] = acc[e] + br[e];
    int i0 = 0;
#pragma unroll
    for (int e = 1; e < 8; e++) if (lg[e] > lg[i0]) i0 = e;
    int i1 = (i0 == 0) ? 1 : 0;
#pragma unroll
    for (int e = 0; e < 8; e++) if (e != i0 && lg[e] > lg[i1]) i1 = e;
    float w0v = 1.f / (1.f + __expf(lg[i1] - lg[i0]));
    float wv[8];
#pragma unroll
    for (int e = 0; e < 8; e++) wv[e] = 0.f;
    wv[i0] = w0v; wv[i1] = 1.f - w0v;
#pragma unroll
    for (int e = 0; e < 8; e++) wgate[(long)token * 8 + e] = wv[e];
    eIdx[token * 2] = i0; eIdx[token * 2 + 1] = i1;
    int b = token >> 11;
    atomicAdd(&segMeta[32 + i0 * 2 + b], 1);
    atomicAdd(&segMeta[32 + i1 * 2 + b], 1);
  }
}

// segMeta layout: [0:16) segStart, [16:32) segPad, [32:48) cnt, [48:64) fill
__global__ void prefix_kernel(int* segMeta) {
  if (threadIdx.x == 0) {
    int s = 0;
    for (int i = 0; i < 16; i++) {
      int c = segMeta[32 + i];
      int p = (c + 127) & ~127;
      segMeta[i] = s; segMeta[16 + i] = p; s += p;
    }
  }
}

__global__ void scatter_kernel(const int* __restrict__ eIdx, int* __restrict__ segMeta,
                               int* __restrict__ tokList, int* __restrict__ posIdx) {
  int t0 = blockIdx.x * 256 + threadIdx.x;
  if (t0 >= TOK) return;
  int b = t0 >> 11;
  for (int k = 0; k < 2; k++) {
    int e = eIdx[t0 * 2 + k];
    int eb = e * 2 + b;
    int pos = atomicAdd(&segMeta[48 + eb], 1);
    int row = segMeta[eb] + pos;
    tokList[row] = t0;
    posIdx[t0 * 2 + k] = row;
  }
}

// out[tok] = OgF[p0] + OgF[p1]  (gated partials already applied)
__global__ void combine_kernel(const u16* __restrict__ Og, const int* __restrict__ posIdx,
                               float* __restrict__ out) {
  const int tok = blockIdx.x;
  const int c = threadIdx.x * 4;
  const long p0 = posIdx[tok * 2], p1 = posIdx[tok * 2 + 1];
  shortx4 a = *(const shortx4*)(Og + p0 * D_DIM + c);
  shortx4 b = *(const shortx4*)(Og + p1 * D_DIM + c);
  float4 o;
  o.x = bf2f((u16)a[0]) + bf2f((u16)b[0]);
  o.y = bf2f((u16)a[1]) + bf2f((u16)b[1]);
  o.z = bf2f((u16)a[2]) + bf2f((u16)b[2]);
  o.w = bf2f((u16)a[3]) + bf2f((u16)b[3]);
  *(float4*)(out + (long)tok * D_DIM + c) = o;
}

// ---------------- GEMM core macro pieces are shared by gemm_bt and qkv_gemm ------------
// GEMM: C[M,N] = A[M,K=1024] x Bt[N,K=1024]^T (+bias)
// AMAP: 0 linear (z=expert); 1 chunk gather (z=expert); 2 tokList gather (z=seg); 3 seg-linear (z=seg)
// EPI : 0 bf16 C; 1 bf16 C transposed per batch; 2 dense gated fp32 atomic; 4 gated bf16 seg-rows
template<int AMAP, int EPI>
__launch_bounds__(256)
__global__ void gemm_bt(const u16* __restrict__ A, long aLeStride,
                        const u16* __restrict__ Bt, const float* __restrict__ bias,
                        u16* __restrict__ Cb, long cLeStride,
                        const float* __restrict__ wgate, float* __restrict__ outAcc,
                        int e0, const int* __restrict__ segMeta,
                        const int* __restrict__ tokList) {
  __shared__ u16 As[128 * 32];
  __shared__ u16 Bs[128 * 32];
  const int t = threadIdx.x;
  const int lane = t & 63, w = t >> 6;
  const int le = blockIdx.z;
  int e; long rowBase = 0; int segCnt = 0;
  if (AMAP >= 2) {
    e = le >> 1;
    int sp = segMeta[16 + le];
    if ((int)(blockIdx.x * 128) >= sp) return;
    rowBase = segMeta[le]; segCnt = segMeta[32 + le];
  } else {
    e = e0 + le;
  }
  const long row0 = (long)blockIdx.x * 128;
  const long col0 = (long)blockIdx.y * 128;

  const u16* Ap = (AMAP <= 1) ? (A + (long)le * aLeStride) : A;
  const u16* Btp = Bt + (long)e * D_DIM * D_DIM;
  const float* biasp = bias + (long)e * D_DIM;

  const u16* aSrc[2];
  const u16* bSrc[2];
#pragma unroll
  for (int i = 0; i < 2; i++) {
    int o = i * 4096 + t * 16;
    int r = o >> 6;
    int slot = ((o >> 4) & 3) ^ ((r >> 1) & 3);
    long r_loc = row0 + r;
    long arow;
    if (AMAP == 1) arow = (r_loc >> 9) * M_KV + (long)e * CHUNK + (r_loc & 511);
    else if (AMAP == 2) arow = tokList[rowBase + (r_loc < segCnt ? r_loc : (long)(segCnt - 1))];
    else if (AMAP == 3) arow = rowBase + r_loc;
    else arow = r_loc;
    aSrc[i] = Ap + arow * D_DIM + slot * 8;
    bSrc[i] = Btp + (col0 + r) * D_DIM + slot * 8;
  }

  f32x4 acc[4][4];
#pragma unroll
  for (int i = 0; i < 4; i++)
#pragma unroll
    for (int j = 0; j < 4; j++) acc[i][j] = (f32x4){0.f, 0.f, 0.f, 0.f};

  const int wr = (w >> 1) * 64, wc = (w & 1) * 64;
  const int fr = lane & 15, fs = lane >> 4;
  int aoff[4], boff[4];
#pragma unroll
  for (int mi = 0; mi < 4; mi++) { int r = wr + mi * 16 + fr; aoff[mi] = r * 32 + ((fs ^ ((r >> 1) & 3)) * 8); }
#pragma unroll
  for (int ni = 0; ni < 4; ni++) { int r = wc + ni * 16 + fr; boff[ni] = r * 32 + ((fs ^ ((r >> 1) & 3)) * 8); }

  char* ldsA = (char*)As + w * 1024;
  char* ldsB = (char*)Bs + w * 1024;

  for (int kb = 0; kb < 32; kb++) {
    __syncthreads();
#pragma unroll
    for (int i = 0; i < 2; i++) gload_lds16(aSrc[i] + kb * 32, ldsA + i * 4096);
#pragma unroll
    for (int i = 0; i < 2; i++) gload_lds16(bSrc[i] + kb * 32, ldsB + i * 4096);
    __syncthreads();
    bf16x8 af[4], bff[4];
#pragma unroll
    for (int mi = 0; mi < 4; mi++) af[mi] = *(const bf16x8*)(As + aoff[mi]);
#pragma unroll
    for (int ni = 0; ni < 4; ni++) bff[ni] = *(const bf16x8*)(Bs + boff[ni]);
#pragma unroll
    for (int mi = 0; mi < 4; mi++)
#pragma unroll
      for (int ni = 0; ni < 4; ni++)
        acc[mi][ni] = __builtin_amdgcn_mfma_f32_16x16x32_bf16(af[mi], bff[ni], acc[mi][ni], 0, 0, 0);
  }

#pragma unroll
  for (int ni = 0; ni < 4; ni++) {
    long c = col0 + wc + ni * 16 + fr;
    float bv = biasp[c];
#pragma unroll
    for (int mi = 0; mi < 4; mi++) {
      long r0g = row0 + wr + mi * 16 + fs * 4;
      f32x4 v = acc[mi][ni];
      if (EPI == 0) {
        u16* Cp = Cb + (AMAP >= 2 ? rowBase * D_DIM : (long)le * cLeStride);
#pragma unroll
        for (int j = 0; j < 4; j++) Cp[(r0g + j) * D_DIM + c] = f2bfu(v[j] + bv);
      } else if (EPI == 1) {
        u16* Cp = Cb + (long)le * cLeStride;
        long b = r0g >> 9, m0 = r0g & 511;
        shortx4 pk;
#pragma unroll
        for (int j = 0; j < 4; j++) pk[j] = (short)f2bfu(v[j] + bv);
        *(shortx4*)(Cp + (b * D_DIM + c) * CHUNK + m0) = pk;
      } else if (EPI == 2) {
#pragma unroll
        for (int j = 0; j < 4; j++) {
          long r = r0g + j;
          float wv = wgate[r * E_EXP + e];
          if (wv != 0.f) atomicAdd(outAcc + r * D_DIM + c, wv * (v[j] + bv));
        }
      } else if (EPI == 4) {
#pragma unroll
        for (int j = 0; j < 4; j++) {
          long rl = r0g + j;
          if (rl < segCnt) {
            int tok = tokList[rowBase + rl];
            float wv = wgate[(long)tok * E_EXP + e];
            Cb[(rowBase + rl) * D_DIM + c] = f2bfu(wv * (v[j] + bv));
          }
        }
      }
    }
  }
}

// ---------------- fused Q/K/V projection (one dispatch) ----------------
// z 0..7:  K-proj expert z   (chunk-gather A from kb, bf16 C -> Kp[e])
// z 8..15: V-proj expert z-8 (chunk-gather A from vb, transposed C -> Vtb[e])
// z 16..31: Q-proj segment z-16 (tokList-gather A from qb, bf16 C -> Qg rows)
__launch_bounds__(256)
__global__ void qkv_gemm(const u16* __restrict__ qb, const u16* __restrict__ kb,
                         const u16* __restrict__ vb,
                         const u16* __restrict__ Wqt, const u16* __restrict__ Wkt,
                         const u16* __restrict__ Wvt,
                         const float* __restrict__ bq, const float* __restrict__ bk,
                         const float* __restrict__ bv,
                         u16* __restrict__ Qg, u16* __restrict__ Kp, u16* __restrict__ Vtb,
                         const int* __restrict__ segMeta, const int* __restrict__ tokList) {
  __shared__ u16 As[128 * 32];
  __shared__ u16 Bs[128 * 32];
  const int t = threadIdx.x;
  const int lane = t & 63, w = t >> 6;
  const int z = blockIdx.z;
  const int role = (z < 8) ? 0 : (z < 16 ? 1 : 2);

  int e; long rowBase = 0; int segCnt = 0;
  const u16* A; const u16* Bt; const float* bias;
  if (role == 0) {
    if (blockIdx.x >= 8) return;
    e = z; A = kb; Bt = Wkt; bias = bk;
  } else if (role == 1) {
    if (blockIdx.x >= 8) return;
    e = z - 8; A = vb; Bt = Wvt; bias = bv;
  } else {
    const int seg = z - 16;
    int sp = segMeta[16 + seg];
    if ((int)(blockIdx.x * 128) >= sp) return;
    e = seg >> 1; rowBase = segMeta[seg]; segCnt = segMeta[32 + seg];
    A = qb; Bt = Wqt; bias = bq;
  }
  const long row0 = (long)blockIdx.x * 128;
  const long col0 = (long)blockIdx.y * 128;
  const u16* Btp = Bt + (long)e * D_DIM * D_DIM;
  const float* biasp = bias + (long)e * D_DIM;

  const u16* aSrc[2];
  const u16* bSrc[2];
#pragma unroll
  for (int i = 0; i < 2; i++) {
    int o = i * 4096 + t * 16;
    int r = o >> 6;
    int slot = ((o >> 4) & 3) ^ ((r >> 1) & 3);
    long r_loc = row0 + r;
    long arow;
    if (role == 2) arow = tokList[rowBase + (r_loc < segCnt ? r_loc : (long)(segCnt - 1))];
    else arow = (r_loc >> 9) * M_KV + (long)e * CHUNK + (r_loc & 511);
    aSrc[i] = A + arow * D_DIM + slot * 8;
    bSrc[i] = Btp + (col0 + r) * D_DIM + slot * 8;
  }

  f32x4 acc[4][4];
#pragma unroll
  for (int i = 0; i < 4; i++)
#pragma unroll
    for (int j = 0; j < 4; j++) acc[i][j] = (f32x4){0.f, 0.f, 0.f, 0.f};

  const int wr = (w >> 1) * 64, wc = (w & 1) * 64;
  const int fr = lane & 15, fs = lane >> 4;
  int aoff[4], boff[4];
#pragma unroll
  for (int mi = 0; mi < 4; mi++) { int r = wr + mi * 16 + fr; aoff[mi] = r * 32 + ((fs ^ ((r >> 1) & 3)) * 8); }
#pragma unroll
  for (int ni = 0; ni < 4; ni++) { int r = wc + ni * 16 + fr; boff[ni] = r * 32 + ((fs ^ ((r >> 1) & 3)) * 8); }

  char* ldsA = (char*)As + w * 1024;
  char* ldsB = (char*)Bs + w * 1024;

  for (int kb2 = 0; kb2 < 32; kb2++) {
    __syncthreads();
#pragma unroll
    for (int i = 0; i < 2; i++) gload_lds16(aSrc[i] + kb2 * 32, ldsA + i * 4096);
#pragma unroll
    for (int i = 0; i < 2; i++) gload_lds16(bSrc[i] + kb2 * 32, ldsB + i * 4096);
    __syncthreads();
    bf16x8 af[4], bff[4];
#pragma unroll
    for (int mi = 0; mi < 4; mi++) af[mi] = *(const bf16x8*)(As + aoff[mi]);
#pragma unroll
    for (int ni = 0; ni < 4; ni++) bff[ni] = *(const bf16x8*)(Bs + boff[ni]);
#pragma unroll
    for (int mi = 0; mi < 4; mi++)
#pragma unroll
      for (int ni = 0; ni < 4; ni++)
        acc[mi][ni] = __builtin_amdgcn_mfma_f32_16x16x32_bf16(af[mi], bff[ni], acc[mi][ni], 0, 0, 0);
  }

#pragma unroll
  for (int ni = 0; ni < 4; ni++) {
    long c = col0 + wc + ni * 16 + fr;
    float bv_ = biasp[c];
#pragma unroll
    for (int mi = 0; mi < 4; mi++) {
      long r0g = row0 + wr + mi * 16 + fs * 4;
      f32x4 v = acc[mi][ni];
      if (role == 0) {
        u16* Cp = Kp + (long)e * KROWS * D_DIM;
#pragma unroll
        for (int j = 0; j < 4; j++) Cp[(r0g + j) * D_DIM + c] = f2bfu(v[j] + bv_);
      } else if (role == 1) {
        u16* Cp = Vtb + (long)e * B_BATCH * D_DIM * CHUNK;
        long b = r0g >> 9, m0 = r0g & 511;
        shortx4 pk;
#pragma unroll
        for (int j = 0; j < 4; j++) pk[j] = (short)f2bfu(v[j] + bv_);
        *(shortx4*)(Cp + (b * D_DIM + c) * CHUNK + m0) = pk;
      } else {
        u16* Cp = Qg + rowBase * D_DIM;
#pragma unroll
        for (int j = 0; j < 4; j++) Cp[(r0g + j) * D_DIM + c] = f2bfu(v[j] + bv_);
      }
    }
  }
}

// ---------------- fused attention ----------------
template<int GATHER>
__launch_bounds__(256)
__global__ void attn_kernel(const u16* __restrict__ Qp, const u16* __restrict__ Kp,
                            const u16* __restrict__ Vt, u16* __restrict__ AO,
                            const int* __restrict__ segMeta) {
  __shared__ u16 Qs[64 * 64];
  __shared__ u16 Ks[128 * 64];
  __shared__ u16 Vs[64 * 128];
  __shared__ u16 Ps[4][16 * 128];

  const int t = threadIdx.x, lane = t & 63, w = t >> 6;

  const u16 *Qbase, *Kbase, *Vbase;
  u16* AObase;
  if (GATHER) {
    const int eb = blockIdx.z, e = eb >> 1, b = eb & 1, h = blockIdx.y;
    int sp = segMeta[16 + eb];
    if ((int)(blockIdx.x * 64) >= sp) return;
    long qrow0 = segMeta[eb] + blockIdx.x * 64;
    Qbase = Qp + qrow0 * D_DIM + h * HD;
    Kbase = Kp + ((long)e * KROWS + (long)b * CHUNK) * D_DIM + h * HD;
    Vbase = Vt + ((long)e * B_BATCH + b) * (long)D_DIM * CHUNK + (long)h * HD * CHUNK;
    AObase = AO + qrow0 * D_DIM + h * HD;
  } else {
    const int qb0 = blockIdx.x * 64;
    const int b = blockIdx.y >> 4, h = blockIdx.y & 15;
    const int le = blockIdx.z;
    Qbase = Qp + (long)le * TOK * D_DIM + ((long)b * N_SEQ + qb0) * D_DIM + h * HD;
    Kbase = Kp + (long)le * KROWS * D_DIM + (long)b * CHUNK * D_DIM + h * HD;
    Vbase = Vt + ((long)le * B_BATCH + b) * (long)D_DIM * CHUNK + (long)h * HD * CHUNK;
    AObase = AO + (long)le * TOK * D_DIM + ((long)b * N_SEQ + qb0) * D_DIM + h * HD;
  }

#pragma unroll
  for (int i = 0; i < 2; i++) {
    int o = i * 4096 + t * 16;
    int r = o >> 7;
    int slot = ((o >> 4) & 7) ^ (r & 7);
    gload_lds16(Qbase + (long)r * D_DIM + slot * 8, (char*)Qs + w * 1024 + i * 4096);
  }

  const int fr = lane & 15, fs = lane >> 4;
  const int qrow = w * 16 + fr;
  int qoff[2];
#pragma unroll
  for (int ks = 0; ks < 2; ks++) qoff[ks] = qrow * 64 + (((ks * 4 + fs) ^ (qrow & 7)) * 8);
  int koff[8][2];
#pragma unroll
  for (int g = 0; g < 8; g++)
#pragma unroll
    for (int ks = 0; ks < 2; ks++) {
      int r = g * 16 + fr;
      koff[g][ks] = r * 64 + (((ks * 4 + fs) ^ (r & 7)) * 8);
    }
  int voff[4][4];
#pragma unroll
  for (int ni = 0; ni < 4; ni++)
#pragma unroll
    for (int ks = 0; ks < 4; ks++) {
      int r = ni * 16 + fr;
      voff[ni][ks] = r * 128 + (((ks * 4 + fs) ^ (r & 7)) * 8);
    }
  int poff[4];
#pragma unroll
  for (int ks = 0; ks < 4; ks++) poff[ks] = fr * 128 + (((ks * 4 + fs) ^ (fr & 7)) * 8);

  float mrun[4], lsum[4];
#pragma unroll
  for (int j = 0; j < 4; j++) { mrun[j] = -1e30f; lsum[j] = 0.f; }
  f32x4 oacc[4];
#pragma unroll
  for (int ni = 0; ni < 4; ni++) oacc[ni] = (f32x4){0.f, 0.f, 0.f, 0.f};

  for (int mt = 0; mt < 4; mt++) {
    __syncthreads();
#pragma unroll
    for (int i = 0; i < 4; i++) {
      int o = i * 4096 + t * 16;
      int r = o >> 7;
      int slot = ((o >> 4) & 7) ^ (r & 7);
      gload_lds16(Kbase + (long)(mt * 128 + r) * D_DIM + slot * 8, (char*)Ks + w * 1024 + i * 4096);
    }
#pragma unroll
    for (int i = 0; i < 4; i++) {
      int o = i * 4096 + t * 16;
      int r = o >> 8;
      int slot = ((o >> 4) & 15) ^ (r & 7);
      gload_lds16(Vbase + (long)r * CHUNK + mt * 128 + slot * 8, (char*)Vs + w * 1024 + i * 4096);
    }
    __syncthreads();

    f32x4 s[8];
#pragma unroll
    for (int g = 0; g < 8; g++) s[g] = (f32x4){0.f, 0.f, 0.f, 0.f};
#pragma unroll
    for (int ks = 0; ks < 2; ks++) {
      bf16x8 aq = *(const bf16x8*)(Qs + qoff[ks]);
#pragma unroll
      for (int g = 0; g < 8; g++) {
        bf16x8 bk = *(const bf16x8*)(Ks + koff[g][ks]);
        s[g] = __builtin_amdgcn_mfma_f32_16x16x32_bf16(aq, bk, s[g], 0, 0, 0);
      }
    }
#pragma unroll
    for (int g = 0; g < 8; g++) s[g] *= 0.125f;

    float tmax[4];
#pragma unroll
    for (int j = 0; j < 4; j++) {
      float mx = s[0][j];
#pragma unroll
      for (int g = 1; g < 8; g++) mx = fmaxf(mx, s[g][j]);
      tmax[j] = mx;
    }
    for (int off = 1; off < 16; off <<= 1)
#pragma unroll
      for (int j = 0; j < 4; j++) tmax[j] = fmaxf(tmax[j], __shfl_xor(tmax[j], off));

    float corr[4];
#pragma unroll
    for (int j = 0; j < 4; j++) {
      float mn = fmaxf(mrun[j], tmax[j]);
      corr[j] = __expf(mrun[j] - mn);
      mrun[j] = mn;
    }
#pragma unroll
    for (int ni = 0; ni < 4; ni++)
#pragma unroll
      for (int j = 0; j < 4; j++) oacc[ni][j] *= corr[j];

    float psum[4] = {0.f, 0.f, 0.f, 0.f};
#pragma unroll
    for (int g = 0; g < 8; g++) {
#pragma unroll
      for (int j = 0; j < 4; j++) {
        float p = __expf(s[g][j] - mrun[j]);
        psum[j] += p;
        int prow = fs * 4 + j;
        int slot = (g * 2 + (fr >> 3)) ^ (prow & 7);
        Ps[w][prow * 128 + slot * 8 + (fr & 7)] = f2bfu(p);
      }
    }
#pragma unroll
    for (int j = 0; j < 4; j++) lsum[j] = lsum[j] * corr[j] + psum[j];

#pragma unroll
    for (int ks = 0; ks < 4; ks++) {
      bf16x8 ap = *(const bf16x8*)(&Ps[w][poff[ks]]);
#pragma unroll
      for (int ni = 0; ni < 4; ni++) {
        bf16x8 bvv = *(const bf16x8*)(Vs + voff[ni][ks]);
        oacc[ni] = __builtin_amdgcn_mfma_f32_16x16x32_bf16(ap, bvv, oacc[ni], 0, 0, 0);
      }
    }
  }

  for (int off = 1; off < 16; off <<= 1)
#pragma unroll
    for (int j = 0; j < 4; j++) lsum[j] += __shfl_xor(lsum[j], off);

#pragma unroll
  for (int ni = 0; ni < 4; ni++) {
    int c = ni * 16 + fr;
#pragma unroll
    for (int j = 0; j < 4; j++) {
      int qr = w * 16 + fs * 4 + j;
      AObase[(long)qr * D_DIM + c] = f2bfu(oacc[ni][j] / lsum[j]);
    }
  }
}

// ---------------- launcher ----------------
extern "C" void kernel_launch(void* const* d_in, const int* in_sizes, int n_in,
                              void* d_out, int out_size, void* d_ws, size_t ws_size,
                              hipStream_t stream) {
  const float* qf = (const float*)d_in[0];
  const float* kf = (const float*)d_in[1];
  const float* vf = (const float*)d_in[2];
  const float* Wq = (const float*)d_in[3];
  const float* bq = (const float*)d_in[4];
  const float* Wk = (const float*)d_in[5];
  const float* bk = (const float*)d_in[6];
  const float* Wv = (const float*)d_in[7];
  const float* bv = (const float*)d_in[8];
  const float* Wo = (const float*)d_in[9];
  const float* bo = (const float*)d_in[10];
  const float* Wr = (const float*)d_in[11];
  const float* br = (const float*)d_in[12];
  float* out = (float*)d_out;

  char* base = (char*)d_ws;
  size_t off = 0;
  auto alloc = [&](size_t bytes) {
    void* r = base + off;
    off += (bytes + 255) & ~(size_t)255;
    return r;
  };
  // common buffers
  u16* qb = (u16*)alloc((size_t)TOK * D_DIM * 2);
  u16* kb = (u16*)alloc((size_t)B_BATCH * M_KV * D_DIM * 2);
  u16* vb = (u16*)alloc((size_t)B_BATCH * M_KV * D_DIM * 2);
  u16* Wqt = (u16*)alloc((size_t)E_EXP * D_DIM * D_DIM * 2);
  u16* Wkt = (u16*)alloc((size_t)E_EXP * D_DIM * D_DIM * 2);
  u16* Wvt = (u16*)alloc((size_t)E_EXP * D_DIM * D_DIM * 2);
  u16* Wot = (u16*)alloc((size_t)E_EXP * D_DIM * D_DIM * 2);
  float* wgate = (float*)alloc((size_t)TOK * E_EXP * 4);
  int* eIdx = (int*)alloc((size_t)TOK * 2 * 4);
  int* segMeta = (int*)alloc(64 * 4);
  int* tokList = (int*)alloc((size_t)LISTROWS * 4);
  int* posIdx = (int*)alloc((size_t)TOK * 2 * 4);
  const size_t mark = off;

  // sparse-path big buffers (dry-run sizing)
  u16* Qg = (u16*)alloc((size_t)LISTROWS * D_DIM * 2);
  u16* Kp = (u16*)alloc((size_t)E_EXP * KROWS * D_DIM * 2);
  u16* Vtb = (u16*)alloc((size_t)E_EXP * B_BATCH * D_DIM * CHUNK * 2);
  u16* AOg = (u16*)alloc((size_t)LISTROWS * D_DIM * 2);
  u16* OgF = Qg;  // Qg dead after attn; O-proj gated partials alias it
  const bool sparse = (off <= ws_size);

  // common prologue
  cast_all<<<20480, 256, 0, stream>>>((const float4*)qf, (const float4*)kf, (const float4*)vf,
                                      (shortx4*)qb, (shortx4*)kb, (shortx4*)vb);
  transpose_cast_all<<<dim3(32, 32, 32), 256, 0, stream>>>(Wq, Wk, Wv, Wo, Wqt, Wkt, Wvt, Wot);
  zero_aux<<<1, 64, 0, stream>>>(segMeta);
  router_kernel<<<TOK / 4, 256, 0, stream>>>(qf, Wr, br, wgate, eIdx, segMeta);

  if (sparse) {
    prefix_kernel<<<1, 64, 0, stream>>>(segMeta);
    scatter_kernel<<<TOK / 256, 256, 0, stream>>>(eIdx, segMeta, tokList, posIdx);
    qkv_gemm<<<dim3(16, 8, 32), 256, 0, stream>>>(qb, kb, vb, Wqt, Wkt, Wvt, bq, bk, bv,
                                                  Qg, Kp, Vtb, segMeta, tokList);
    attn_kernel<1><<<dim3(N_SEQ / 64, H_HEADS, 16), 256, 0, stream>>>(Qg, Kp, Vtb, AOg, segMeta);
    gemm_bt<3, 4><<<dim3(N_SEQ / 128, 8, 16), 256, 0, stream>>>(
        AOg, 0L, Wot, bo, OgF, 0L, wgate, nullptr, 0, segMeta, tokList);
    combine_kernel<<<TOK, 256, 0, stream>>>(OgF, posIdx, out);
  } else {
    // dense fallback (round-2 verified path)
    zero_f32<<<TOK * D_DIM / 4 / 256, 256, 0, stream>>>((float4*)out, TOK * D_DIM / 4);
    size_t offd = mark;
    auto alloc2 = [&](size_t bytes) {
      void* r = base + offd;
      offd += (bytes + 255) & ~(size_t)255;
      return r;
    };
    size_t perE = 2 * (size_t)TOK * D_DIM * 2 + (size_t)KROWS * D_DIM * 2 +
                  (size_t)B_BATCH * D_DIM * CHUNK * 2;
    int G = 8;
    while (G > 1 && mark + (size_t)G * (perE + 2048) > ws_size) G >>= 1;
    u16* Qp = (u16*)alloc2((size_t)G * TOK * D_DIM * 2);
    u16* Kpd = (u16*)alloc2((size_t)G * KROWS * D_DIM * 2);
    u16* Vtd = (u16*)alloc2((size_t)G * B_BATCH * D_DIM * CHUNK * 2);
    u16* AOb = (u16*)alloc2((size_t)G * TOK * D_DIM * 2);
    for (int e0 = 0; e0 < E_EXP; e0 += G) {
      gemm_bt<0, 0><<<dim3(TOK / 128, 8, G), 256, 0, stream>>>(
          qb, 0L, Wqt, bq, Qp, (long)TOK * D_DIM, nullptr, nullptr, e0, nullptr, nullptr);
      gemm_bt<1, 0><<<dim3(KROWS / 128, 8, G), 256, 0, stream>>>(
          kb, 0L, Wkt, bk, Kpd, (long)KROWS * D_DIM, nullptr, nullptr, e0, nullptr, nullptr);
      gemm_bt<1, 1><<<dim3(KROWS / 128, 8, G), 256, 0, stream>>>(
          vb, 0L, Wvt, bv, Vtd, (long)B_BATCH * D_DIM * CHUNK, nullptr, nullptr, e0, nullptr, nullptr);
      attn_kernel<0><<<dim3(N_SEQ / 64, B_BATCH * H_HEADS, G), 256, 0, stream>>>(Qp, Kpd, Vtd, AOb, nullptr);
      gemm_bt<0, 2><<<dim3(TOK / 128, 8, G), 256, 0, stream>>>(
          AOb, (long)TOK * D_DIM, Wot, bo, nullptr, 0L, wgate, out, e0, nullptr, nullptr);
    }
  }
  (void)in_sizes; (void)n_in; (void)out_size;
}

// Round 6
// 596.514 us; speedup vs baseline: 1.6947x; 1.4972x over previous
//
#include <hip/hip_runtime.h>
#include <hip/hip_bf16.h>
#include <stdint.h>

#define D_DIM 1024
#define H_HEADS 16
#define HD 64
#define E_EXP 8
#define B_BATCH 2
#define N_SEQ 2048
#define M_KV 4096
#define CHUNK 512
#define TOK (B_BATCH*N_SEQ)
#define KROWS (B_BATCH*CHUNK)
#define LISTROWS 10240  // >= TOK*2 + 16*127 padded rows

typedef unsigned short u16;
typedef __attribute__((ext_vector_type(8))) short bf16x8;
typedef __attribute__((ext_vector_type(4))) float f32x4;
typedef __attribute__((ext_vector_type(4))) short shortx4;

__device__ __forceinline__ u16 f2bfu(float x) {
  unsigned int u = __float_as_uint(x);
  u += 0x7FFF + ((u >> 16) & 1);
  return (u16)(u >> 16);
}
__device__ __forceinline__ float bf2f(u16 v) {
  return __uint_as_float(((unsigned)v) << 16);
}

__device__ __forceinline__ void gload_lds16(const u16* g, char* lds_base) {
  __builtin_amdgcn_global_load_lds(
      (const __attribute__((address_space(1))) void*)g,
      (__attribute__((address_space(3))) void*)lds_base, 16, 0, 0);
}

// ---------------- utility kernels ----------------

__global__ void zero_f32(float4* out, int n4) {
  int i = blockIdx.x * 256 + threadIdx.x;
  if (i < n4) out[i] = make_float4(0.f, 0.f, 0.f, 0.f);
}

__global__ void zero_aux(int* p) { p[threadIdx.x] = 0; }  // 64 threads

// merged cast of q (4096 f4-blocks), k (8192), v (8192)
__global__ void cast_all(const float4* __restrict__ qf, const float4* __restrict__ kf,
                         const float4* __restrict__ vf, shortx4* __restrict__ qb,
                         shortx4* __restrict__ kb, shortx4* __restrict__ vb) {
  int blk = blockIdx.x;
  const float4* in; shortx4* out; int i;
  if (blk < 4096) { in = qf; out = qb; i = blk * 256 + threadIdx.x; }
  else if (blk < 12288) { in = kf; out = kb; i = (blk - 4096) * 256 + threadIdx.x; }
  else { in = vf; out = vb; i = (blk - 12288) * 256 + threadIdx.x; }
  float4 v = in[i];
  shortx4 p;
  p[0] = (short)f2bfu(v.x); p[1] = (short)f2bfu(v.y);
  p[2] = (short)f2bfu(v.z); p[3] = (short)f2bfu(v.w);
  out[i] = p;
}

// W[e][k][n] fp32 -> Wt[e][n][k] bf16 ; z = which*8 + e
__global__ void transpose_cast_all(const float* __restrict__ Wq, const float* __restrict__ Wk,
                                   const float* __restrict__ Wv, const float* __restrict__ Wo,
                                   u16* __restrict__ Wqt, u16* __restrict__ Wkt,
                                   u16* __restrict__ Wvt, u16* __restrict__ Wot) {
  __shared__ float tile[32][33];
  const int which = blockIdx.z >> 3, e = blockIdx.z & 7;
  const float* W = which == 0 ? Wq : which == 1 ? Wk : which == 2 ? Wv : Wo;
  u16* Wt = which == 0 ? Wqt : which == 1 ? Wkt : which == 2 ? Wvt : Wot;
  const int kb = blockIdx.x * 32;
  const int nb = blockIdx.y * 32;
  const int tx = threadIdx.x & 31, ty = threadIdx.x >> 5;
  const float* Wp = W + (long)e * D_DIM * D_DIM;
  u16* Wtp = Wt + (long)e * D_DIM * D_DIM;
#pragma unroll
  for (int i = 0; i < 4; i++) {
    int r = ty + i * 8;
    tile[r][tx] = Wp[(long)(kb + r) * D_DIM + nb + tx];
  }
  __syncthreads();
#pragma unroll
  for (int i = 0; i < 4; i++) {
    int n = ty + i * 8;
    Wtp[(long)(nb + n) * D_DIM + kb + tx] = f2bfu(tile[tx][n]);
  }
}

// ---------------- router ----------------
__launch_bounds__(256)
__global__ void router_kernel(const float* __restrict__ q, const float* __restrict__ Wr,
                              const float* __restrict__ br, float* __restrict__ wgate,
                              int* __restrict__ eIdx, int* __restrict__ segMeta) {
  const int lane = threadIdx.x & 63, w = threadIdx.x >> 6;
  const int token = blockIdx.x * 4 + w;
  float acc[E_EXP];
#pragma unroll
  for (int e = 0; e < 8; e++) acc[e] = 0.f;
  const float* qp = q + (long)token * D_DIM;
  for (int it = 0; it < 16; it++) {
    int d = it * 64 + lane;
    float qv = qp[d];
    const float4* wr4 = (const float4*)(Wr + (long)d * 8);
    float4 w0 = wr4[0], w1 = wr4[1];
    acc[0] += qv * w0.x; acc[1] += qv * w0.y; acc[2] += qv * w0.z; acc[3] += qv * w0.w;
    acc[4] += qv * w1.x; acc[5] += qv * w1.y; acc[6] += qv * w1.z; acc[7] += qv * w1.w;
  }
#pragma unroll
  for (int e = 0; e < 8; e++)
    for (int off = 32; off; off >>= 1) acc[e] += __shfl_down(acc[e], off);
  if (lane == 0) {
    float lg[8];
#pragma unroll
    for (int e = 0; e < 8; e++) lg[e] = acc[e] + br[e];
    int i0 = 0;
#pragma unroll
    for (int e = 1; e < 8; e++) if (lg[e] > lg[i0]) i0 = e;
    int i1 = (i0 == 0) ? 1 : 0;
#pragma unroll
    for (int e = 0; e < 8; e++) if (e != i0 && lg[e] > lg[i1]) i1 = e;
    float w0v = 1.f / (1.f + __expf(lg[i1] - lg[i0]));
    float wv[8];
#pragma unroll
    for (int e = 0; e < 8; e++) wv[e] = 0.f;
    wv[i0] = w0v; wv[i1] = 1.f - w0v;
#pragma unroll
    for (int e = 0; e < 8; e++) wgate[(long)token * 8 + e] = wv[e];
    eIdx[token * 2] = i0; eIdx[token * 2 + 1] = i1;
    int b = token >> 11;
    atomicAdd(&segMeta[32 + i0 * 2 + b], 1);
    atomicAdd(&segMeta[32 + i1 * 2 + b], 1);
  }
}

// segMeta layout: [0:16) segStart, [16:32) segPad, [32:48) cnt, [48:64) fill
__global__ void prefix_kernel(int* segMeta) {
  if (threadIdx.x == 0) {
    int s = 0;
    for (int i = 0; i < 16; i++) {
      int c = segMeta[32 + i];
      int p = (c + 127) & ~127;
      segMeta[i] = s; segMeta[16 + i] = p; s += p;
    }
  }
}

__global__ void scatter_kernel(const int* __restrict__ eIdx, int* __restrict__ segMeta,
                               int* __restrict__ tokList, int* __restrict__ posIdx) {
  int t0 = blockIdx.x * 256 + threadIdx.x;
  if (t0 >= TOK) return;
  int b = t0 >> 11;
  for (int k = 0; k < 2; k++) {
    int e = eIdx[t0 * 2 + k];
    int eb = e * 2 + b;
    int pos = atomicAdd(&segMeta[48 + eb], 1);
    int row = segMeta[eb] + pos;
    tokList[row] = t0;
    posIdx[t0 * 2 + k] = row;
  }
}

// out[tok] = OgF[p0] + OgF[p1]  (gated partials already applied)
__global__ void combine_kernel(const u16* __restrict__ Og, const int* __restrict__ posIdx,
                               float* __restrict__ out) {
  const int tok = blockIdx.x;
  const int c = threadIdx.x * 4;
  const long p0 = posIdx[tok * 2], p1 = posIdx[tok * 2 + 1];
  shortx4 a = *(const shortx4*)(Og + p0 * D_DIM + c);
  shortx4 b = *(const shortx4*)(Og + p1 * D_DIM + c);
  float4 o;
  o.x = bf2f((u16)a[0]) + bf2f((u16)b[0]);
  o.y = bf2f((u16)a[1]) + bf2f((u16)b[1]);
  o.z = bf2f((u16)a[2]) + bf2f((u16)b[2]);
  o.w = bf2f((u16)a[3]) + bf2f((u16)b[3]);
  *(float4*)(out + (long)tok * D_DIM + c) = o;
}

// ---------------- GEMM: C[M,N] = A[M,K=1024] x Bt[N,K=1024]^T (+bias) ----------------
// AMAP: 0 linear (z=expert); 1 chunk gather (z=expert); 2 tokList gather (z=seg); 3 seg-linear (z=seg)
// EPI : 0 bf16 C; 1 bf16 C transposed per batch; 2 dense gated fp32 atomic; 4 gated bf16 seg-rows
// For AMAP>=2 the grid is (x=col-tile, y=row-tile) so weight-panel sharers (same x, same e)
// are spaced gridDim.x apart in dispatch order -> same XCD -> L2 reuse. AMAP<=1 keeps (x=row,y=col).
template<int AMAP, int EPI>
__launch_bounds__(256)
__global__ void gemm_bt(const u16* __restrict__ A, long aLeStride,
                        const u16* __restrict__ Bt, const float* __restrict__ bias,
                        u16* __restrict__ Cb, long cLeStride,
                        const float* __restrict__ wgate, float* __restrict__ outAcc,
                        int e0, const int* __restrict__ segMeta,
                        const int* __restrict__ tokList) {
  __shared__ u16 As[128 * 32];
  __shared__ u16 Bs[128 * 32];
  const int t = threadIdx.x;
  const int lane = t & 63, w = t >> 6;
  const int le = blockIdx.z;
  const int rowBlk = (AMAP >= 2) ? blockIdx.y : blockIdx.x;
  const int colBlk = (AMAP >= 2) ? blockIdx.x : blockIdx.y;
  int e; long rowBase = 0; int segCnt = 0;
  if (AMAP >= 2) {
    e = le >> 1;
    int sp = segMeta[16 + le];
    if (rowBlk * 128 >= sp) return;
    rowBase = segMeta[le]; segCnt = segMeta[32 + le];
  } else {
    e = e0 + le;
  }
  const long row0 = (long)rowBlk * 128;
  const long col0 = (long)colBlk * 128;

  const u16* Ap = (AMAP <= 1) ? (A + (long)le * aLeStride) : A;
  const u16* Btp = Bt + (long)e * D_DIM * D_DIM;
  const float* biasp = bias + (long)e * D_DIM;

  const u16* aSrc[2];
  const u16* bSrc[2];
#pragma unroll
  for (int i = 0; i < 2; i++) {
    int o = i * 4096 + t * 16;
    int r = o >> 6;
    int slot = ((o >> 4) & 3) ^ ((r >> 1) & 3);
    long r_loc = row0 + r;
    long arow;
    if (AMAP == 1) arow = (r_loc >> 9) * M_KV + (long)e * CHUNK + (r_loc & 511);
    else if (AMAP == 2) arow = tokList[rowBase + (r_loc < segCnt ? r_loc : (long)(segCnt - 1))];
    else if (AMAP == 3) arow = rowBase + r_loc;
    else arow = r_loc;
    aSrc[i] = Ap + arow * D_DIM + slot * 8;
    bSrc[i] = Btp + (col0 + r) * D_DIM + slot * 8;
  }

  f32x4 acc[4][4];
#pragma unroll
  for (int i = 0; i < 4; i++)
#pragma unroll
    for (int j = 0; j < 4; j++) acc[i][j] = (f32x4){0.f, 0.f, 0.f, 0.f};

  const int wr = (w >> 1) * 64, wc = (w & 1) * 64;
  const int fr = lane & 15, fs = lane >> 4;
  int aoff[4], boff[4];
#pragma unroll
  for (int mi = 0; mi < 4; mi++) { int r = wr + mi * 16 + fr; aoff[mi] = r * 32 + ((fs ^ ((r >> 1) & 3)) * 8); }
#pragma unroll
  for (int ni = 0; ni < 4; ni++) { int r = wc + ni * 16 + fr; boff[ni] = r * 32 + ((fs ^ ((r >> 1) & 3)) * 8); }

  char* ldsA = (char*)As + w * 1024;
  char* ldsB = (char*)Bs + w * 1024;

  for (int kb = 0; kb < 32; kb++) {
    __syncthreads();
#pragma unroll
    for (int i = 0; i < 2; i++) gload_lds16(aSrc[i] + kb * 32, ldsA + i * 4096);
#pragma unroll
    for (int i = 0; i < 2; i++) gload_lds16(bSrc[i] + kb * 32, ldsB + i * 4096);
    __syncthreads();
    bf16x8 af[4], bff[4];
#pragma unroll
    for (int mi = 0; mi < 4; mi++) af[mi] = *(const bf16x8*)(As + aoff[mi]);
#pragma unroll
    for (int ni = 0; ni < 4; ni++) bff[ni] = *(const bf16x8*)(Bs + boff[ni]);
#pragma unroll
    for (int mi = 0; mi < 4; mi++)
#pragma unroll
      for (int ni = 0; ni < 4; ni++)
        acc[mi][ni] = __builtin_amdgcn_mfma_f32_16x16x32_bf16(af[mi], bff[ni], acc[mi][ni], 0, 0, 0);
  }

#pragma unroll
  for (int ni = 0; ni < 4; ni++) {
    long c = col0 + wc + ni * 16 + fr;
    float bv = biasp[c];
#pragma unroll
    for (int mi = 0; mi < 4; mi++) {
      long r0g = row0 + wr + mi * 16 + fs * 4;
      f32x4 v = acc[mi][ni];
      if (EPI == 0) {
        u16* Cp = Cb + (AMAP >= 2 ? rowBase * D_DIM : (long)le * cLeStride);
#pragma unroll
        for (int j = 0; j < 4; j++) Cp[(r0g + j) * D_DIM + c] = f2bfu(v[j] + bv);
      } else if (EPI == 1) {
        u16* Cp = Cb + (long)le * cLeStride;
        long b = r0g >> 9, m0 = r0g & 511;
        shortx4 pk;
#pragma unroll
        for (int j = 0; j < 4; j++) pk[j] = (short)f2bfu(v[j] + bv);
        *(shortx4*)(Cp + (b * D_DIM + c) * CHUNK + m0) = pk;
      } else if (EPI == 2) {
#pragma unroll
        for (int j = 0; j < 4; j++) {
          long r = r0g + j;
          float wv = wgate[r * E_EXP + e];
          if (wv != 0.f) atomicAdd(outAcc + r * D_DIM + c, wv * (v[j] + bv));
        }
      } else if (EPI == 4) {
#pragma unroll
        for (int j = 0; j < 4; j++) {
          long rl = r0g + j;
          if (rl < segCnt) {
            int tok = tokList[rowBase + rl];
            float wv = wgate[(long)tok * E_EXP + e];
            Cb[(rowBase + rl) * D_DIM + c] = f2bfu(wv * (v[j] + bv));
          }
        }
      }
    }
  }
}

// ---------------- fused Q/K/V projection (one dispatch) ----------------
// grid (x=col-tile 8, y=row-tile 16, z=role)
// z 0..7:  K-proj expert z   (chunk-gather A from kb, bf16 C -> Kp[e]) ; rows 0..1023 (y<8)
// z 8..15: V-proj expert z-8 (chunk-gather A from vb, transposed C -> Vtb[e]) ; y<8
// z 16..31: Q-proj segment z-16 (tokList-gather A from qb, bf16 C -> Qg rows) ; y*128<segPad
__launch_bounds__(256)
__global__ void qkv_gemm(const u16* __restrict__ qb, const u16* __restrict__ kb,
                         const u16* __restrict__ vb,
                         const u16* __restrict__ Wqt, const u16* __restrict__ Wkt,
                         const u16* __restrict__ Wvt,
                         const float* __restrict__ bq, const float* __restrict__ bk,
                         const float* __restrict__ bv,
                         u16* __restrict__ Qg, u16* __restrict__ Kp, u16* __restrict__ Vtb,
                         const int* __restrict__ segMeta, const int* __restrict__ tokList) {
  __shared__ u16 As[128 * 32];
  __shared__ u16 Bs[128 * 32];
  const int t = threadIdx.x;
  const int lane = t & 63, w = t >> 6;
  const int z = blockIdx.z;
  const int role = (z < 8) ? 0 : (z < 16 ? 1 : 2);
  const int rowBlk = blockIdx.y, colBlk = blockIdx.x;

  int e; long rowBase = 0; int segCnt = 0;
  const u16* A; const u16* Bt; const float* bias;
  if (role == 0) {
    if (rowBlk >= 8) return;
    e = z; A = kb; Bt = Wkt; bias = bk;
  } else if (role == 1) {
    if (rowBlk >= 8) return;
    e = z - 8; A = vb; Bt = Wvt; bias = bv;
  } else {
    const int seg = z - 16;
    int sp = segMeta[16 + seg];
    if (rowBlk * 128 >= sp) return;
    e = seg >> 1; rowBase = segMeta[seg]; segCnt = segMeta[32 + seg];
    A = qb; Bt = Wqt; bias = bq;
  }
  const long row0 = (long)rowBlk * 128;
  const long col0 = (long)colBlk * 128;
  const u16* Btp = Bt + (long)e * D_DIM * D_DIM;
  const float* biasp = bias + (long)e * D_DIM;

  const u16* aSrc[2];
  const u16* bSrc[2];
#pragma unroll
  for (int i = 0; i < 2; i++) {
    int o = i * 4096 + t * 16;
    int r = o >> 6;
    int slot = ((o >> 4) & 3) ^ ((r >> 1) & 3);
    long r_loc = row0 + r;
    long arow;
    if (role == 2) arow = tokList[rowBase + (r_loc < segCnt ? r_loc : (long)(segCnt - 1))];
    else arow = (r_loc >> 9) * M_KV + (long)e * CHUNK + (r_loc & 511);
    aSrc[i] = A + arow * D_DIM + slot * 8;
    bSrc[i] = Btp + (col0 + r) * D_DIM + slot * 8;
  }

  f32x4 acc[4][4];
#pragma unroll
  for (int i = 0; i < 4; i++)
#pragma unroll
    for (int j = 0; j < 4; j++) acc[i][j] = (f32x4){0.f, 0.f, 0.f, 0.f};

  const int wr = (w >> 1) * 64, wc = (w & 1) * 64;
  const int fr = lane & 15, fs = lane >> 4;
  int aoff[4], boff[4];
#pragma unroll
  for (int mi = 0; mi < 4; mi++) { int r = wr + mi * 16 + fr; aoff[mi] = r * 32 + ((fs ^ ((r >> 1) & 3)) * 8); }
#pragma unroll
  for (int ni = 0; ni < 4; ni++) { int r = wc + ni * 16 + fr; boff[ni] = r * 32 + ((fs ^ ((r >> 1) & 3)) * 8); }

  char* ldsA = (char*)As + w * 1024;
  char* ldsB = (char*)Bs + w * 1024;

  for (int kb2 = 0; kb2 < 32; kb2++) {
    __syncthreads();
#pragma unroll
    for (int i = 0; i < 2; i++) gload_lds16(aSrc[i] + kb2 * 32, ldsA + i * 4096);
#pragma unroll
    for (int i = 0; i < 2; i++) gload_lds16(bSrc[i] + kb2 * 32, ldsB + i * 4096);
    __syncthreads();
    bf16x8 af[4], bff[4];
#pragma unroll
    for (int mi = 0; mi < 4; mi++) af[mi] = *(const bf16x8*)(As + aoff[mi]);
#pragma unroll
    for (int ni = 0; ni < 4; ni++) bff[ni] = *(const bf16x8*)(Bs + boff[ni]);
#pragma unroll
    for (int mi = 0; mi < 4; mi++)
#pragma unroll
      for (int ni = 0; ni < 4; ni++)
        acc[mi][ni] = __builtin_amdgcn_mfma_f32_16x16x32_bf16(af[mi], bff[ni], acc[mi][ni], 0, 0, 0);
  }

#pragma unroll
  for (int ni = 0; ni < 4; ni++) {
    long c = col0 + wc + ni * 16 + fr;
    float bv_ = biasp[c];
#pragma unroll
    for (int mi = 0; mi < 4; mi++) {
      long r0g = row0 + wr + mi * 16 + fs * 4;
      f32x4 v = acc[mi][ni];
      if (role == 0) {
        u16* Cp = Kp + (long)e * KROWS * D_DIM;
#pragma unroll
        for (int j = 0; j < 4; j++) Cp[(r0g + j) * D_DIM + c] = f2bfu(v[j] + bv_);
      } else if (role == 1) {
        u16* Cp = Vtb + (long)e * B_BATCH * D_DIM * CHUNK;
        long b = r0g >> 9, m0 = r0g & 511;
        shortx4 pk;
#pragma unroll
        for (int j = 0; j < 4; j++) pk[j] = (short)f2bfu(v[j] + bv_);
        *(shortx4*)(Cp + (b * D_DIM + c) * CHUNK + m0) = pk;
      } else {
        u16* Cp = Qg + rowBase * D_DIM;
#pragma unroll
        for (int j = 0; j < 4; j++) Cp[(r0g + j) * D_DIM + c] = f2bfu(v[j] + bv_);
      }
    }
  }
}

// ---------------- fused attention ----------------
// GATHER=1: grid (x = eb*16+h [256], y = q-tile [32]). K/V-slice sharers have the same x
// -> linear ids spaced 256 apart -> same XCD -> L2-warm; early exits form a contiguous tail.
// GATHER=0 (dense fallback): original (x=qtile, y=b*16+h, z=expert-slot).
template<int GATHER>
__launch_bounds__(256)
__global__ void attn_kernel(const u16* __restrict__ Qp, const u16* __restrict__ Kp,
                            const u16* __restrict__ Vt, u16* __restrict__ AO,
                            const int* __restrict__ segMeta) {
  __shared__ u16 Qs[64 * 64];
  __shared__ u16 Ks[128 * 64];
  __shared__ u16 Vs[64 * 128];
  __shared__ u16 Ps[4][16 * 128];

  const int t = threadIdx.x, lane = t & 63, w = t >> 6;

  const u16 *Qbase, *Kbase, *Vbase;
  u16* AObase;
  if (GATHER) {
    const int eh = blockIdx.x;
    const int eb = eh >> 4, h = eh & 15;
    const int e = eb >> 1, b = eb & 1;
    int sp = segMeta[16 + eb];
    if ((int)(blockIdx.y * 64) >= sp) return;
    long qrow0 = segMeta[eb] + blockIdx.y * 64;
    Qbase = Qp + qrow0 * D_DIM + h * HD;
    Kbase = Kp + ((long)e * KROWS + (long)b * CHUNK) * D_DIM + h * HD;
    Vbase = Vt + ((long)e * B_BATCH + b) * (long)D_DIM * CHUNK + (long)h * HD * CHUNK;
    AObase = AO + qrow0 * D_DIM + h * HD;
  } else {
    const int qb0 = blockIdx.x * 64;
    const int b = blockIdx.y >> 4, h = blockIdx.y & 15;
    const int le = blockIdx.z;
    Qbase = Qp + (long)le * TOK * D_DIM + ((long)b * N_SEQ + qb0) * D_DIM + h * HD;
    Kbase = Kp + (long)le * KROWS * D_DIM + (long)b * CHUNK * D_DIM + h * HD;
    Vbase = Vt + ((long)le * B_BATCH + b) * (long)D_DIM * CHUNK + (long)h * HD * CHUNK;
    AObase = AO + (long)le * TOK * D_DIM + ((long)b * N_SEQ + qb0) * D_DIM + h * HD;
  }

#pragma unroll
  for (int i = 0; i < 2; i++) {
    int o = i * 4096 + t * 16;
    int r = o >> 7;
    int slot = ((o >> 4) & 7) ^ (r & 7);
    gload_lds16(Qbase + (long)r * D_DIM + slot * 8, (char*)Qs + w * 1024 + i * 4096);
  }

  const int fr = lane & 15, fs = lane >> 4;
  const int qrow = w * 16 + fr;
  int qoff[2];
#pragma unroll
  for (int ks = 0; ks < 2; ks++) qoff[ks] = qrow * 64 + (((ks * 4 + fs) ^ (qrow & 7)) * 8);
  int koff[8][2];
#pragma unroll
  for (int g = 0; g < 8; g++)
#pragma unroll
    for (int ks = 0; ks < 2; ks++) {
      int r = g * 16 + fr;
      koff[g][ks] = r * 64 + (((ks * 4 + fs) ^ (r & 7)) * 8);
    }
  int voff[4][4];
#pragma unroll
  for (int ni = 0; ni < 4; ni++)
#pragma unroll
    for (int ks = 0; ks < 4; ks++) {
      int r = ni * 16 + fr;
      voff[ni][ks] = r * 128 + (((ks * 4 + fs) ^ (r & 7)) * 8);
    }
  int poff[4];
#pragma unroll
  for (int ks = 0; ks < 4; ks++) poff[ks] = fr * 128 + (((ks * 4 + fs) ^ (fr & 7)) * 8);

  float mrun[4], lsum[4];
#pragma unroll
  for (int j = 0; j < 4; j++) { mrun[j] = -1e30f; lsum[j] = 0.f; }
  f32x4 oacc[4];
#pragma unroll
  for (int ni = 0; ni < 4; ni++) oacc[ni] = (f32x4){0.f, 0.f, 0.f, 0.f};

  for (int mt = 0; mt < 4; mt++) {
    __syncthreads();
#pragma unroll
    for (int i = 0; i < 4; i++) {
      int o = i * 4096 + t * 16;
      int r = o >> 7;
      int slot = ((o >> 4) & 7) ^ (r & 7);
      gload_lds16(Kbase + (long)(mt * 128 + r) * D_DIM + slot * 8, (char*)Ks + w * 1024 + i * 4096);
    }
#pragma unroll
    for (int i = 0; i < 4; i++) {
      int o = i * 4096 + t * 16;
      int r = o >> 8;
      int slot = ((o >> 4) & 15) ^ (r & 7);
      gload_lds16(Vbase + (long)r * CHUNK + mt * 128 + slot * 8, (char*)Vs + w * 1024 + i * 4096);
    }
    __syncthreads();

    f32x4 s[8];
#pragma unroll
    for (int g = 0; g < 8; g++) s[g] = (f32x4){0.f, 0.f, 0.f, 0.f};
#pragma unroll
    for (int ks = 0; ks < 2; ks++) {
      bf16x8 aq = *(const bf16x8*)(Qs + qoff[ks]);
#pragma unroll
      for (int g = 0; g < 8; g++) {
        bf16x8 bk = *(const bf16x8*)(Ks + koff[g][ks]);
        s[g] = __builtin_amdgcn_mfma_f32_16x16x32_bf16(aq, bk, s[g], 0, 0, 0);
      }
    }
#pragma unroll
    for (int g = 0; g < 8; g++) s[g] *= 0.125f;

    float tmax[4];
#pragma unroll
    for (int j = 0; j < 4; j++) {
      float mx = s[0][j];
#pragma unroll
      for (int g = 1; g < 8; g++) mx = fmaxf(mx, s[g][j]);
      tmax[j] = mx;
    }
    for (int off = 1; off < 16; off <<= 1)
#pragma unroll
      for (int j = 0; j < 4; j++) tmax[j] = fmaxf(tmax[j], __shfl_xor(tmax[j], off));

    float corr[4];
#pragma unroll
    for (int j = 0; j < 4; j++) {
      float mn = fmaxf(mrun[j], tmax[j]);
      corr[j] = __expf(mrun[j] - mn);
      mrun[j] = mn;
    }
#pragma unroll
    for (int ni = 0; ni < 4; ni++)
#pragma unroll
      for (int j = 0; j < 4; j++) oacc[ni][j] *= corr[j];

    float psum[4] = {0.f, 0.f, 0.f, 0.f};
#pragma unroll
    for (int g = 0; g < 8; g++) {
#pragma unroll
      for (int j = 0; j < 4; j++) {
        float p = __expf(s[g][j] - mrun[j]);
        psum[j] += p;
        int prow = fs * 4 + j;
        int slot = (g * 2 + (fr >> 3)) ^ (prow & 7);
        Ps[w][prow * 128 + slot * 8 + (fr & 7)] = f2bfu(p);
      }
    }
#pragma unroll
    for (int j = 0; j < 4; j++) lsum[j] = lsum[j] * corr[j] + psum[j];

#pragma unroll
    for (int ks = 0; ks < 4; ks++) {
      bf16x8 ap = *(const bf16x8*)(&Ps[w][poff[ks]]);
#pragma unroll
      for (int ni = 0; ni < 4; ni++) {
        bf16x8 bvv = *(const bf16x8*)(Vs + voff[ni][ks]);
        oacc[ni] = __builtin_amdgcn_mfma_f32_16x16x32_bf16(ap, bvv, oacc[ni], 0, 0, 0);
      }
    }
  }

  for (int off = 1; off < 16; off <<= 1)
#pragma unroll
    for (int j = 0; j < 4; j++) lsum[j] += __shfl_xor(lsum[j], off);

#pragma unroll
  for (int ni = 0; ni < 4; ni++) {
    int c = ni * 16 + fr;
#pragma unroll
    for (int j = 0; j < 4; j++) {
      int qr = w * 16 + fs * 4 + j;
      AObase[(long)qr * D_DIM + c] = f2bfu(oacc[ni][j] / lsum[j]);
    }
  }
}

// ---------------- launcher ----------------
extern "C" void kernel_launch(void* const* d_in, const int* in_sizes, int n_in,
                              void* d_out, int out_size, void* d_ws, size_t ws_size,
                              hipStream_t stream) {
  const float* qf = (const float*)d_in[0];
  const float* kf = (const float*)d_in[1];
  const float* vf = (const float*)d_in[2];
  const float* Wq = (const float*)d_in[3];
  const float* bq = (const float*)d_in[4];
  const float* Wk = (const float*)d_in[5];
  const float* bk = (const float*)d_in[6];
  const float* Wv = (const float*)d_in[7];
  const float* bv = (const float*)d_in[8];
  const float* Wo = (const float*)d_in[9];
  const float* bo = (const float*)d_in[10];
  const float* Wr = (const float*)d_in[11];
  const float* br = (const float*)d_in[12];
  float* out = (float*)d_out;

  char* base = (char*)d_ws;
  size_t off = 0;
  auto alloc = [&](size_t bytes) {
    void* r = base + off;
    off += (bytes + 255) & ~(size_t)255;
    return r;
  };
  // common buffers
  u16* qb = (u16*)alloc((size_t)TOK * D_DIM * 2);
  u16* kb = (u16*)alloc((size_t)B_BATCH * M_KV * D_DIM * 2);
  u16* vb = (u16*)alloc((size_t)B_BATCH * M_KV * D_DIM * 2);
  u16* Wqt = (u16*)alloc((size_t)E_EXP * D_DIM * D_DIM * 2);
  u16* Wkt = (u16*)alloc((size_t)E_EXP * D_DIM * D_DIM * 2);
  u16* Wvt = (u16*)alloc((size_t)E_EXP * D_DIM * D_DIM * 2);
  u16* Wot = (u16*)alloc((size_t)E_EXP * D_DIM * D_DIM * 2);
  float* wgate = (float*)alloc((size_t)TOK * E_EXP * 4);
  int* eIdx = (int*)alloc((size_t)TOK * 2 * 4);
  int* segMeta = (int*)alloc(64 * 4);
  int* tokList = (int*)alloc((size_t)LISTROWS * 4);
  int* posIdx = (int*)alloc((size_t)TOK * 2 * 4);
  const size_t mark = off;

  // sparse-path big buffers (dry-run sizing)
  u16* Qg = (u16*)alloc((size_t)LISTROWS * D_DIM * 2);
  u16* Kp = (u16*)alloc((size_t)E_EXP * KROWS * D_DIM * 2);
  u16* Vtb = (u16*)alloc((size_t)E_EXP * B_BATCH * D_DIM * CHUNK * 2);
  u16* AOg = (u16*)alloc((size_t)LISTROWS * D_DIM * 2);
  u16* OgF = Qg;  // Qg dead after attn; O-proj gated partials alias it
  const bool sparse = (off <= ws_size);

  // common prologue
  cast_all<<<20480, 256, 0, stream>>>((const float4*)qf, (const float4*)kf, (const float4*)vf,
                                      (shortx4*)qb, (shortx4*)kb, (shortx4*)vb);
  transpose_cast_all<<<dim3(32, 32, 32), 256, 0, stream>>>(Wq, Wk, Wv, Wo, Wqt, Wkt, Wvt, Wot);
  zero_aux<<<1, 64, 0, stream>>>(segMeta);
  router_kernel<<<TOK / 4, 256, 0, stream>>>(qf, Wr, br, wgate, eIdx, segMeta);

  if (sparse) {
    prefix_kernel<<<1, 64, 0, stream>>>(segMeta);
    scatter_kernel<<<TOK / 256, 256, 0, stream>>>(eIdx, segMeta, tokList, posIdx);
    qkv_gemm<<<dim3(8, 16, 32), 256, 0, stream>>>(qb, kb, vb, Wqt, Wkt, Wvt, bq, bk, bv,
                                                  Qg, Kp, Vtb, segMeta, tokList);
    attn_kernel<1><<<dim3(256, 32, 1), 256, 0, stream>>>(Qg, Kp, Vtb, AOg, segMeta);
    gemm_bt<3, 4><<<dim3(8, 16, 16), 256, 0, stream>>>(
        AOg, 0L, Wot, bo, OgF, 0L, wgate, nullptr, 0, segMeta, tokList);
    combine_kernel<<<TOK, 256, 0, stream>>>(OgF, posIdx, out);
  } else {
    // dense fallback (round-2 verified path)
    zero_f32<<<TOK * D_DIM / 4 / 256, 256, 0, stream>>>((float4*)out, TOK * D_DIM / 4);
    size_t offd = mark;
    auto alloc2 = [&](size_t bytes) {
      void* r = base + offd;
      offd += (bytes + 255) & ~(size_t)255;
      return r;
    };
    size_t perE = 2 * (size_t)TOK * D_DIM * 2 + (size_t)KROWS * D_DIM * 2 +
                  (size_t)B_BATCH * D_DIM * CHUNK * 2;
    int G = 8;
    while (G > 1 && mark + (size_t)G * (perE + 2048) > ws_size) G >>= 1;
    u16* Qp = (u16*)alloc2((size_t)G * TOK * D_DIM * 2);
    u16* Kpd = (u16*)alloc2((size_t)G * KROWS * D_DIM * 2);
    u16* Vtd = (u16*)alloc2((size_t)G * B_BATCH * D_DIM * CHUNK * 2);
    u16* AOb = (u16*)alloc2((size_t)G * TOK * D_DIM * 2);
    for (int e0 = 0; e0 < E_EXP; e0 += G) {
      gemm_bt<0, 0><<<dim3(TOK / 128, 8, G), 256, 0, stream>>>(
          qb, 0L, Wqt, bq, Qp, (long)TOK * D_DIM, nullptr, nullptr, e0, nullptr, nullptr);
      gemm_bt<1, 0><<<dim3(KROWS / 128, 8, G), 256, 0, stream>>>(
          kb, 0L, Wkt, bk, Kpd, (long)KROWS * D_DIM, nullptr, nullptr, e0, nullptr, nullptr);
      gemm_bt<1, 1><<<dim3(KROWS / 128, 8, G), 256, 0, stream>>>(
          vb, 0L, Wvt, bv, Vtd, (long)B_BATCH * D_DIM * CHUNK, nullptr, nullptr, e0, nullptr, nullptr);
      attn_kernel<0><<<dim3(N_SEQ / 64, B_BATCH * H_HEADS, G), 256, 0, stream>>>(Qp, Kpd, Vtd, AOb, nullptr);
      gemm_bt<0, 2><<<dim3(TOK / 128, 8, G), 256, 0, stream>>>(
          AOb, (long)TOK * D_DIM, Wot, bo, nullptr, 0L, wgate, out, e0, nullptr, nullptr);
    }
  }
  (void)in_sizes; (void)n_in; (void)out_size;
}